// Round 3
// baseline (391.198 us; speedup 1.0000x reference)
//
#include <hip/hip_runtime.h>

typedef unsigned short u16;
typedef unsigned char u8;
typedef float f32x4 __attribute__((ext_vector_type(4)));

#define P_OUT 29791      // 31^3
#define PPAD  29824      // 233*128
#define NBAT  4
#define NCH   512
#define KDIM  128

// ---- pack 4 fp32 -> 4 fp8 e4m3 (RNE, OCP) ----
__device__ __forceinline__ unsigned pk4_fp8(float a, float b, float c, float d) {
  int v = __builtin_amdgcn_cvt_pk_fp8_f32(a, b, 0, false);   // low word
  v = __builtin_amdgcn_cvt_pk_fp8_f32(c, d, v, true);        // high word
  return (unsigned)v;
}

// ---- fused prep ----
// blocks [0, 3844): y-prep, one block per (nb, d, h): stage x slab
//   [16c][2dd][2hh][32w] (8 KB) in LDS coalesced, pack 31 fp8 rows + ysq.
// blocks [3844, 3876): w-prep (512 rows, 16 rows/block).
__global__ void prep_kernel(const float* __restrict__ x,
                            const float* __restrict__ w,
                            u8* __restrict__ yb, float* __restrict__ ysq,
                            u8* __restrict__ wb, float* __restrict__ wsq) {
  const int tid = threadIdx.x;
  const int b = blockIdx.x;
  if (b >= 3844) {   // ---- w-prep ----
    const int g = (b - 3844) * 16 + (tid >> 4);  // 0..511
    const int c = tid & 15;
    const float4* wr = (const float4*)(w + g * 128 + c * 8);
    float4 f0 = wr[0], f1 = wr[1];
    float s = f0.x*f0.x + f0.y*f0.y + f0.z*f0.z + f0.w*f0.w
            + f1.x*f1.x + f1.y*f1.y + f1.z*f1.z + f1.w*f1.w;
#pragma unroll
    for (int m = 1; m < 16; m <<= 1) s += __shfl_xor(s, m, 64);
    uint2 pk;
    pk.x = pk4_fp8(f0.x, f0.y, f0.z, f0.w);
    pk.y = pk4_fp8(f1.x, f1.y, f1.z, f1.w);
    *(uint2*)(wb + g * 128 + c * 8) = pk;
    if (c == 0) wsq[g] = s;
    return;
  }
  // ---- y-prep ----
  __shared__ float xs[16][4][33];   // [c][r=kd*2+kh][w], +1 pad -> 2-way max
  const int nb = b / 961;
  const int rem = b - nb * 961;
  const int d = rem / 31;
  const int h = rem - d * 31;
  const float* xb = x + ((size_t)nb << 19) + d * 1024 + h * 32;
  // load 2048 floats, fully coalesced (contiguous 128 B per (c,r))
#pragma unroll
  for (int t = 0; t < 8; ++t) {
    const int e = tid + 256 * t;
    const int c = e >> 7;
    const int r = (e >> 5) & 3;
    const int wv = e & 31;
    xs[c][r][wv] = xb[((size_t)c << 15) + (r >> 1) * 1024 + (r & 1) * 32 + wv];
  }
  __syncthreads();
  const int cs = tid & 15;    // channel = k-chunk of 8
  const int wv0 = tid >> 4;
#pragma unroll
  for (int round = 0; round < 2; ++round) {
    const int wv = wv0 + 16 * round;
    if (wv <= 30) {           // uniform per 16-lane group
      const float v0 = xs[cs][0][wv], v1 = xs[cs][0][wv + 1];
      const float v2 = xs[cs][1][wv], v3 = xs[cs][1][wv + 1];
      const float v4 = xs[cs][2][wv], v5 = xs[cs][2][wv + 1];
      const float v6 = xs[cs][3][wv], v7 = xs[cs][3][wv + 1];
      float s = v0*v0 + v1*v1 + v2*v2 + v3*v3 + v4*v4 + v5*v5 + v6*v6 + v7*v7;
#pragma unroll
      for (int m = 1; m < 16; m <<= 1) s += __shfl_xor(s, m, 64);
      const int g = nb * PPAD + d * 961 + h * 31 + wv;
      uint2 pk;
      pk.x = pk4_fp8(v0, v1, v2, v3);
      pk.y = pk4_fp8(v4, v5, v6, v7);
      *(uint2*)(yb + (size_t)g * 128 + cs * 8) = pk;
      if (cs == 0) ysq[g] = s;
    }
  }
}

// async global->LDS, 16 B per lane, lands at ldsbase + lane*16
#define GLDS(g, l) __builtin_amdgcn_global_load_lds(                         \
    (const __attribute__((address_space(1))) unsigned int*)(g),              \
    (__attribute__((address_space(3))) unsigned int*)(l), 16, 0, 0)

// ---- GEMM + epilogue: out[n][ch][p] = exp(2*y.w - ysq[p] - wsq[ch]) ----
// One-shot block per tile (verified-fast structure): single 32 KB LDS stage,
// ONE barrier, stores fire-and-forget to kernel end (never drained).
// fp8 e4m3 operands, 4 ks-steps of mfma_f32_16x16x32_fp8_fp8.
// A = w (m=ch), B = y (n=p); C/D col(lane&15)=p contiguous, 64 B segments.
// LDS: [row][8 chunks of 16 B], chunk pos = chunk ^ (row&7).
__global__ void gauss_gemm_kernel(const u8* __restrict__ yb,
                                  const float* __restrict__ ysq,
                                  const u8* __restrict__ wb,
                                  const float* __restrict__ wsq,
                                  float* __restrict__ out) {
  __shared__ __align__(16) u8 Ws[128 * 128];  // w tile [ch][k], 16 KB
  __shared__ __align__(16) u8 Ys[128 * 128];  // y tile [p][k],  16 KB

  const int bid = blockIdx.x;
  const int ct = bid & 3;            // 4 ch tiles
  const int pt = (bid >> 2) % 233;   // 233 p tiles
  const int nb = bid / 932;          // 4 batches
  const int p0 = pt * 128;
  const int c0 = ct * 128;

  const int tid = threadIdx.x;
  const int wid = tid >> 6;
  const int lane = tid & 63;
  const int quad = lane >> 4;
  const int col = lane & 15;
  const int wch = wid & 1;   // wave ch-half
  const int wp = wid >> 1;   // wave p-half

  const size_t ybase = ((size_t)nb * PPAD + p0) * 128;   // bytes

  // ---- stage full K: 1024 chunks of 16 B per tile, 4 rounds each ----
#pragma unroll
  for (int t = 0; t < 4; ++t) {
    const int Lb = (wid * 4 + t) * 64;      // chunk base (wave-uniform)
    const int L = Lb + lane;
    const int row = L >> 3;                 // 8 chunks per 128 B row
    const int jc = (L & 7) ^ (row & 7);     // unswizzled 16B k-chunk
    GLDS(wb + (size_t)(c0 + row) * 128 + jc * 16, &Ws[Lb * 16]);
    GLDS(yb + ybase + (size_t)row * 128 + jc * 16, &Ys[Lb * 16]);
  }

  // ---- ysq prefetch + acc init: independent of LDS, hides under the drain
  float ysv[4];
  int pj[4];
#pragma unroll
  for (int j = 0; j < 4; ++j) {
    pj[j] = p0 + wp * 64 + j * 16 + col;
    ysv[j] = ysq[(size_t)nb * PPAD + pj[j]];
  }

  f32x4 acc[4][4];
#pragma unroll
  for (int i = 0; i < 4; ++i)
#pragma unroll
    for (int j = 0; j < 4; ++j) acc[i][j] = (f32x4){0.f, 0.f, 0.f, 0.f};

  __syncthreads();   // drains GLDS (vmcnt) + all lanes ready

  const int c16b = quad >> 1;   // lane's 16B-chunk offset within ks window
  const int hoff = (quad & 1) * 8;
#pragma unroll
  for (int ks = 0; ks < 4; ++ks) {
    long long a[4], b[4];
#pragma unroll
    for (int i = 0; i < 4; ++i) {
      const int rowA = wch * 64 + i * 16 + col;
      const int pa = (ks * 2 + c16b) ^ (rowA & 7);
      a[i] = *(const long long*)&Ws[rowA * 128 + pa * 16 + hoff];
      const int rowB = wp * 64 + i * 16 + col;
      const int pb = (ks * 2 + c16b) ^ (rowB & 7);
      b[i] = *(const long long*)&Ys[rowB * 128 + pb * 16 + hoff];
    }
#pragma unroll
    for (int i = 0; i < 4; ++i)
#pragma unroll
      for (int j = 0; j < 4; ++j)
        acc[i][j] = __builtin_amdgcn_mfma_f32_16x16x32_fp8_fp8(a[i], b[j],
                                                               acc[i][j], 0, 0, 0);
  }
  // no trailing barrier: stores below are fire-and-forget to kernel end

  // ---- epilogue: out = exp(2*cross - ysq - wsq), nontemporal (never re-read)
  const bool full = (p0 + 128 <= P_OUT);   // 232 of 233 p-tiles
  if (full) {
#pragma unroll
    for (int i = 0; i < 4; ++i) {
#pragma unroll
      for (int r = 0; r < 4; ++r) {
        const int ch = c0 + wch * 64 + i * 16 + quad * 4 + r;
        const float wsv = wsq[ch];
        float* ob = out + ((size_t)(nb * NCH + ch)) * P_OUT;
#pragma unroll
        for (int j = 0; j < 4; ++j)
          __builtin_nontemporal_store(__expf(2.f * acc[i][j][r] - ysv[j] - wsv),
                                      &ob[pj[j]]);
      }
    }
  } else {
#pragma unroll
    for (int i = 0; i < 4; ++i) {
#pragma unroll
      for (int r = 0; r < 4; ++r) {
        const int ch = c0 + wch * 64 + i * 16 + quad * 4 + r;
        const float wsv = wsq[ch];
        float* ob = out + ((size_t)(nb * NCH + ch)) * P_OUT;
#pragma unroll
        for (int j = 0; j < 4; ++j)
          if (pj[j] < P_OUT)
            ob[pj[j]] = __expf(2.f * acc[i][j][r] - ysv[j] - wsv);
      }
    }
  }
}

extern "C" void kernel_launch(void* const* d_in, const int* in_sizes, int n_in,
                              void* d_out, int out_size, void* d_ws, size_t ws_size,
                              hipStream_t stream) {
  const float* x = (const float*)d_in[0];
  const float* w = (const float*)d_in[1];
  float* out = (float*)d_out;
  char* ws = (char*)d_ws;
  // workspace layout (128B-aligned):
  u8* yb     = (u8*)ws;                      // 4*29824*128 fp8 = 15,269,888 B
  float* ysq = (float*)(ws + 15269888);      // 119,296 * 4     =    477,184 B
  u8* wb     = (u8*)(ws + 15747072);         // 512*128 fp8     =     65,536 B
  float* wsq = (float*)(ws + 15812608);      // 512*4           =      2,048 B

  prep_kernel<<<3876, 256, 0, stream>>>(x, w, yb, ysq, wb, wsq);
  gauss_gemm_kernel<<<3728, 256, 0, stream>>>(yb, ysq, wb, wsq, out);
}

// Round 4
// 274.831 us; speedup vs baseline: 1.4234x; 1.4234x over previous
//
#include <hip/hip_runtime.h>

typedef unsigned short u16;
typedef unsigned char u8;
typedef float f32x4 __attribute__((ext_vector_type(4)));

#define P_OUT 29791      // 31^3
#define PPAD  29824      // 233*128
#define NBAT  4
#define NCH   512
#define KDIM  128

// ---- pack 4 fp32 -> 4 fp8 e4m3 (RNE, OCP) ----
__device__ __forceinline__ unsigned pk4_fp8(float a, float b, float c, float d) {
  int v = __builtin_amdgcn_cvt_pk_fp8_f32(a, b, 0, false);   // low word
  v = __builtin_amdgcn_cvt_pk_fp8_f32(c, d, v, true);        // high word
  return (unsigned)v;
}

// ---- fused prep ----
// blocks [0, 3844): y-prep, one block per (nb, d, h): stage x slab
//   [16c][2dd][2hh][32w] (8 KB) in LDS coalesced, pack 31 fp8 rows + ysq.
// blocks [3844, 3876): w-prep (512 rows, 16 rows/block).
__global__ void prep_kernel(const float* __restrict__ x,
                            const float* __restrict__ w,
                            u8* __restrict__ yb, float* __restrict__ ysq,
                            u8* __restrict__ wb, float* __restrict__ wsq) {
  const int tid = threadIdx.x;
  const int b = blockIdx.x;
  if (b >= 3844) {   // ---- w-prep ----
    const int g = (b - 3844) * 16 + (tid >> 4);  // 0..511
    const int c = tid & 15;
    const float4* wr = (const float4*)(w + g * 128 + c * 8);
    float4 f0 = wr[0], f1 = wr[1];
    float s = f0.x*f0.x + f0.y*f0.y + f0.z*f0.z + f0.w*f0.w
            + f1.x*f1.x + f1.y*f1.y + f1.z*f1.z + f1.w*f1.w;
#pragma unroll
    for (int m = 1; m < 16; m <<= 1) s += __shfl_xor(s, m, 64);
    uint2 pk;
    pk.x = pk4_fp8(f0.x, f0.y, f0.z, f0.w);
    pk.y = pk4_fp8(f1.x, f1.y, f1.z, f1.w);
    *(uint2*)(wb + g * 128 + c * 8) = pk;
    if (c == 0) wsq[g] = s;
    return;
  }
  // ---- y-prep ----
  __shared__ float xs[16][4][33];   // [c][r=kd*2+kh][w], +1 pad -> 2-way max
  const int nb = b / 961;
  const int rem = b - nb * 961;
  const int d = rem / 31;
  const int h = rem - d * 31;
  const float* xb = x + ((size_t)nb << 19) + d * 1024 + h * 32;
  // load 2048 floats, fully coalesced (contiguous 128 B per (c,r))
#pragma unroll
  for (int t = 0; t < 8; ++t) {
    const int e = tid + 256 * t;
    const int c = e >> 7;
    const int r = (e >> 5) & 3;
    const int wv = e & 31;
    xs[c][r][wv] = xb[((size_t)c << 15) + (r >> 1) * 1024 + (r & 1) * 32 + wv];
  }
  __syncthreads();
  const int cs = tid & 15;    // channel = k-chunk of 8
  const int wv0 = tid >> 4;
#pragma unroll
  for (int round = 0; round < 2; ++round) {
    const int wv = wv0 + 16 * round;
    if (wv <= 30) {           // uniform per 16-lane group
      const float v0 = xs[cs][0][wv], v1 = xs[cs][0][wv + 1];
      const float v2 = xs[cs][1][wv], v3 = xs[cs][1][wv + 1];
      const float v4 = xs[cs][2][wv], v5 = xs[cs][2][wv + 1];
      const float v6 = xs[cs][3][wv], v7 = xs[cs][3][wv + 1];
      float s = v0*v0 + v1*v1 + v2*v2 + v3*v3 + v4*v4 + v5*v5 + v6*v6 + v7*v7;
#pragma unroll
      for (int m = 1; m < 16; m <<= 1) s += __shfl_xor(s, m, 64);
      const int g = nb * PPAD + d * 961 + h * 31 + wv;
      uint2 pk;
      pk.x = pk4_fp8(v0, v1, v2, v3);
      pk.y = pk4_fp8(v4, v5, v6, v7);
      *(uint2*)(yb + (size_t)g * 128 + cs * 8) = pk;
      if (cs == 0) ysq[g] = s;
    }
  }
}

// async global->LDS, 16 B per lane, lands at ldsbase + lane*16
#define GLDS(g, l) __builtin_amdgcn_global_load_lds(                         \
    (const __attribute__((address_space(1))) unsigned int*)(g),              \
    (__attribute__((address_space(3))) unsigned int*)(l), 16, 0, 0)

// ---- GEMM + epilogue: out[n][ch][p] = exp(2*y.w - ysq[p] - wsq[ch]) ----
// One-shot block per tile (verified-fast structure): single 32 KB LDS stage,
// ONE barrier, stores fire-and-forget to kernel end (never drained).
// Tile decode is XCD-chunked (bijective, 3728 = 8*466): each XCD gets a
// contiguous run of tiles with pt fastest, so consecutive p-tiles of the
// same output rows merge their shared boundary cache lines in that XCD's L2
// (P_OUT=29791 misaligns every ch row; without this the 512 B tile-row
// stretches RMW partial lines at both ends).
// fp8 e4m3 operands, 4 ks-steps of mfma_f32_16x16x32_fp8_fp8.
// A = w (m=ch), B = y (n=p); C/D col(lane&15)=p contiguous, 64 B segments.
// LDS: [row][8 chunks of 16 B], chunk pos = chunk ^ (row&7).
__global__ void gauss_gemm_kernel(const u8* __restrict__ yb,
                                  const float* __restrict__ ysq,
                                  const u8* __restrict__ wb,
                                  const float* __restrict__ wsq,
                                  float* __restrict__ out) {
  __shared__ __align__(16) u8 Ws[128 * 128];  // w tile [ch][k], 16 KB
  __shared__ __align__(16) u8 Ys[128 * 128];  // y tile [p][k],  16 KB

  const int bid = blockIdx.x;
  // bijective XCD-chunked swizzle: xcd = bid&7 (HW round-robins XCDs),
  // each XCD owns 466 consecutive tiles of the (nb, ct, pt) space.
  const int tile = (bid & 7) * 466 + (bid >> 3);
  const int nb = tile / 932;               // 4 batches
  const int rem = tile - nb * 932;
  const int ct = rem / 233;                // 4 ch tiles
  const int pt = rem - ct * 233;           // 233 p tiles, fastest
  const int p0 = pt * 128;
  const int c0 = ct * 128;

  const int tid = threadIdx.x;
  const int wid = tid >> 6;
  const int lane = tid & 63;
  const int quad = lane >> 4;
  const int col = lane & 15;
  const int wch = wid & 1;   // wave ch-half
  const int wp = wid >> 1;   // wave p-half

  const size_t ybase = ((size_t)nb * PPAD + p0) * 128;   // bytes

  // ---- stage full K: 1024 chunks of 16 B per tile, 4 rounds each ----
#pragma unroll
  for (int t = 0; t < 4; ++t) {
    const int Lb = (wid * 4 + t) * 64;      // chunk base (wave-uniform)
    const int L = Lb + lane;
    const int row = L >> 3;                 // 8 chunks per 128 B row
    const int jc = (L & 7) ^ (row & 7);     // unswizzled 16B k-chunk
    GLDS(wb + (size_t)(c0 + row) * 128 + jc * 16, &Ws[Lb * 16]);
    GLDS(yb + ybase + (size_t)row * 128 + jc * 16, &Ys[Lb * 16]);
  }

  // ---- ysq prefetch + acc init: independent of LDS, hides under the drain
  float ysv[4];
  int pj[4];
#pragma unroll
  for (int j = 0; j < 4; ++j) {
    pj[j] = p0 + wp * 64 + j * 16 + col;
    ysv[j] = ysq[(size_t)nb * PPAD + pj[j]];
  }

  f32x4 acc[4][4];
#pragma unroll
  for (int i = 0; i < 4; ++i)
#pragma unroll
    for (int j = 0; j < 4; ++j) acc[i][j] = (f32x4){0.f, 0.f, 0.f, 0.f};

  __syncthreads();   // drains GLDS (vmcnt) + all lanes ready

  const int c16b = quad >> 1;   // lane's 16B-chunk offset within ks window
  const int hoff = (quad & 1) * 8;
#pragma unroll
  for (int ks = 0; ks < 4; ++ks) {
    long long a[4], b[4];
#pragma unroll
    for (int i = 0; i < 4; ++i) {
      const int rowA = wch * 64 + i * 16 + col;
      const int pa = (ks * 2 + c16b) ^ (rowA & 7);
      a[i] = *(const long long*)&Ws[rowA * 128 + pa * 16 + hoff];
      const int rowB = wp * 64 + i * 16 + col;
      const int pb = (ks * 2 + c16b) ^ (rowB & 7);
      b[i] = *(const long long*)&Ys[rowB * 128 + pb * 16 + hoff];
    }
#pragma unroll
    for (int i = 0; i < 4; ++i)
#pragma unroll
      for (int j = 0; j < 4; ++j)
        acc[i][j] = __builtin_amdgcn_mfma_f32_16x16x32_fp8_fp8(a[i], b[j],
                                                               acc[i][j], 0, 0, 0);
  }
  // no trailing barrier: stores below are fire-and-forget to kernel end

  // ---- epilogue: out = exp(2*cross - ysq - wsq), normal stores (L2-merged)
  const bool full = (p0 + 128 <= P_OUT);   // 232 of 233 p-tiles
  if (full) {
#pragma unroll
    for (int i = 0; i < 4; ++i) {
#pragma unroll
      for (int r = 0; r < 4; ++r) {
        const int ch = c0 + wch * 64 + i * 16 + quad * 4 + r;
        const float wsv = wsq[ch];
        float* ob = out + ((size_t)(nb * NCH + ch)) * P_OUT;
#pragma unroll
        for (int j = 0; j < 4; ++j)
          ob[pj[j]] = __expf(2.f * acc[i][j][r] - ysv[j] - wsv);
      }
    }
  } else {
#pragma unroll
    for (int i = 0; i < 4; ++i) {
#pragma unroll
      for (int r = 0; r < 4; ++r) {
        const int ch = c0 + wch * 64 + i * 16 + quad * 4 + r;
        const float wsv = wsq[ch];
        float* ob = out + ((size_t)(nb * NCH + ch)) * P_OUT;
#pragma unroll
        for (int j = 0; j < 4; ++j)
          if (pj[j] < P_OUT)
            ob[pj[j]] = __expf(2.f * acc[i][j][r] - ysv[j] - wsv);
      }
    }
  }
}

extern "C" void kernel_launch(void* const* d_in, const int* in_sizes, int n_in,
                              void* d_out, int out_size, void* d_ws, size_t ws_size,
                              hipStream_t stream) {
  const float* x = (const float*)d_in[0];
  const float* w = (const float*)d_in[1];
  float* out = (float*)d_out;
  char* ws = (char*)d_ws;
  // workspace layout (128B-aligned):
  u8* yb     = (u8*)ws;                      // 4*29824*128 fp8 = 15,269,888 B
  float* ysq = (float*)(ws + 15269888);      // 119,296 * 4     =    477,184 B
  u8* wb     = (u8*)(ws + 15747072);         // 512*128 fp8     =     65,536 B
  float* wsq = (float*)(ws + 15812608);      // 512*4           =      2,048 B

  prep_kernel<<<3876, 256, 0, stream>>>(x, w, yb, ysq, wb, wsq);
  gauss_gemm_kernel<<<3728, 256, 0, stream>>>(yb, ysq, wb, wsq, out);
}

// Round 5
// 268.730 us; speedup vs baseline: 1.4557x; 1.0227x over previous
//
#include <hip/hip_runtime.h>

typedef unsigned char u8;
typedef float f32x4 __attribute__((ext_vector_type(4)));

#define P_OUT 29791      // 31^3
#define NCH   512

// ---- pack 4 fp32 -> 4 fp8 e4m3 (RNE, OCP) ----
__device__ __forceinline__ unsigned pk4_fp8(float a, float b, float c, float d) {
  int v = __builtin_amdgcn_cvt_pk_fp8_f32(a, b, 0, false);   // low word
  v = __builtin_amdgcn_cvt_pk_fp8_f32(c, d, v, true);        // high word
  return (unsigned)v;
}

// ---- w-prep: 512 rows, 16 rows/block, 32 blocks ----
__global__ void wprep_kernel(const float* __restrict__ w,
                             u8* __restrict__ wb, float* __restrict__ wsq) {
  const int tid = threadIdx.x;
  const int g = blockIdx.x * 16 + (tid >> 4);  // 0..511
  const int c = tid & 15;
  const float4* wr = (const float4*)(w + g * 128 + c * 8);
  float4 f0 = wr[0], f1 = wr[1];
  float s = f0.x*f0.x + f0.y*f0.y + f0.z*f0.z + f0.w*f0.w
          + f1.x*f1.x + f1.y*f1.y + f1.z*f1.z + f1.w*f1.w;
#pragma unroll
  for (int m = 1; m < 16; m <<= 1) s += __shfl_xor(s, m, 64);
  uint2 pk;
  pk.x = pk4_fp8(f0.x, f0.y, f0.z, f0.w);
  pk.y = pk4_fp8(f1.x, f1.y, f1.z, f1.w);
  *(uint2*)(wb + g * 128 + c * 8) = pk;
  if (c == 0) wsq[g] = s;
}

// async global->LDS, 16 B per lane, lands at ldsbase + lane*16
#define GLDS(g, l) __builtin_amdgcn_global_load_lds(                         \
    (const __attribute__((address_space(1))) unsigned int*)(g),              \
    (__attribute__((address_space(3))) unsigned int*)(l), 16, 0, 0)

// ---- Fused unfold + GEMM + epilogue ----
// Tile = (nb, ct, d, hb): 128 ch x 124 p (4 h-rows x 31 w; hb=7 -> 93).
// p = d*961 + h*31 + wv is LINEAR in rowB = hh*31+wv -> contiguous stores.
// x slab [16c][2kd][5hq][32w] fp32 (20 KB) staged via GLDS; each lane builds
// its fp8 B-fragment (k = ks*32+quad*8+j, j=(kd,kh,kw)) straight from LDS:
// y[p][k] = x[c][d+kd][h+kh][wv+kw], c = k>>3 = ks*4+quad. ysq computed
// in-register during the pack (fp32, pre-quantization) + quad shfl-reduce.
// A-side (Ws) staging/swizzle + MFMA core + epilogue formula verbatim from
// the verified r4 kernel. XCD-chunked bijective decode: 3968 = 8*496.
__global__ __launch_bounds__(256, 2)
void gauss_fused_kernel(const float* __restrict__ x,
                        const u8* __restrict__ wb,
                        const float* __restrict__ wsq,
                        float* __restrict__ out) {
  __shared__ __align__(16) u8 Ws[128 * 128];        // w tile [ch][k], 16 KB
  __shared__ __align__(16) float Xs[16 * 2 * 5 * 32]; // x slab, 20 KB

  const int bid = blockIdx.x;
  const int tile = (bid & 7) * 496 + (bid >> 3);   // bijective XCD chunking
  const unsigned nb = (unsigned)tile / 992u;       // 4 batches
  const unsigned rem = (unsigned)tile - nb * 992u;
  const unsigned ct = rem / 248u;                  // 4 ch tiles
  const unsigned r2 = rem - ct * 248u;
  const unsigned d  = r2 >> 3;                     // 31 d values
  const unsigned hb = r2 & 7;                      // 8 h-blocks, fastest
  const int h0 = hb * 4;
  const int nh = (h0 + 4 <= 31) ? 4 : (31 - h0);   // 4 (hb<7) or 3 (hb=7)
  const int nrows = nh * 31;                       // 124 or 93
  const int c0 = ct * 128;
  const int tp0 = d * 961 + h0 * 31;               // tile's base p

  const int tid = threadIdx.x;
  const int wid = tid >> 6;
  const int lane = tid & 63;
  const int quad = lane >> 4;
  const int col = lane & 15;
  const int wch = wid & 1;   // wave ch-half
  const int wp = wid >> 1;   // wave p-half

  // ---- stage W tile: 1024 chunks, swizzled (verbatim from r4) ----
#pragma unroll
  for (int t = 0; t < 4; ++t) {
    const int Lb = (wid * 4 + t) * 64;
    const int L = Lb + lane;
    const int row = L >> 3;
    const int jc = (L & 7) ^ (row & 7);
    GLDS(wb + (size_t)(c0 + row) * 128 + jc * 16, &Ws[Lb * 16]);
  }

  // ---- stage x slab: 160 rows of 128 B = 1280 chunks, 5 rounds ----
  // row = c*10 + kd*5 + hq ; global h clamped to 31 (hb=7 tail, slot unused)
#pragma unroll
  for (int t = 0; t < 5; ++t) {
    const int Lb = t * 256 + wid * 64;     // wave-uniform chunk base
    const int L = Lb + lane;
    const int row = L >> 3;                // 0..159
    const int jc = L & 7;                  // 16B chunk within 128 B row
    const unsigned c = (unsigned)row / 10u;
    const unsigned rr = (unsigned)row - c * 10u;
    const unsigned kd = rr / 5u;
    const unsigned hq = rr - kd * 5u;
    const int hg = h0 + (int)hq;
    const int hcl = (hg < 31) ? hg : 31;
    GLDS(x + (((size_t)(nb * 16 + c)) << 15) + (d + kd) * 1024 + hcl * 32 + jc * 4,
         &Xs[Lb * 4]);
  }

  // ---- per-lane p-row decode (independent of LDS; hides under drain) ----
  int rb[4];        // true row in tile
  int xoff[4];      // clamped LDS offset hh*32+wv
#pragma unroll
  for (int j = 0; j < 4; ++j) {
    rb[j] = wp * 64 + j * 16 + col;
    const unsigned rc = (unsigned)((rb[j] < nrows) ? rb[j] : (nrows - 1));
    const unsigned hh = rc / 31u;
    const unsigned wv = rc - hh * 31u;
    xoff[j] = (int)(hh * 32 + wv);
  }

  f32x4 acc[4][4];
#pragma unroll
  for (int i = 0; i < 4; ++i)
#pragma unroll
    for (int j = 0; j < 4; ++j) acc[i][j] = (f32x4){0.f, 0.f, 0.f, 0.f};

  float sq[4] = {0.f, 0.f, 0.f, 0.f};

  __syncthreads();   // drains all GLDS

  const int c16b = quad >> 1;
  const int hoff = (quad & 1) * 8;
#pragma unroll
  for (int ks = 0; ks < 4; ++ks) {
    long long a[4], b[4];
#pragma unroll
    for (int i = 0; i < 4; ++i) {
      const int rowA = wch * 64 + i * 16 + col;
      const int pa = (ks * 2 + c16b) ^ (rowA & 7);
      a[i] = *(const long long*)&Ws[rowA * 128 + pa * 16 + hoff];
    }
    const int cc = ks * 4 + quad;          // channel for this lane's k-chunk
    const float* xb = &Xs[cc * 320];       // [kd][hq][32] view
#pragma unroll
    for (int j = 0; j < 4; ++j) {
      const float* pB = xb + xoff[j];
      // j bits = (kd,kh,kw): strides kd=160, kh=32, kw=1 floats
      const float v0 = pB[0],   v1 = pB[1],   v2 = pB[32],  v3 = pB[33];
      const float v4 = pB[160], v5 = pB[161], v6 = pB[192], v7 = pB[193];
      sq[j] += v0*v0 + v1*v1 + v2*v2 + v3*v3 + v4*v4 + v5*v5 + v6*v6 + v7*v7;
      const unsigned lo = pk4_fp8(v0, v1, v2, v3);
      const unsigned hi = pk4_fp8(v4, v5, v6, v7);
      b[j] = (long long)(((unsigned long long)hi << 32) | lo);
    }
#pragma unroll
    for (int i = 0; i < 4; ++i)
#pragma unroll
      for (int j = 0; j < 4; ++j)
        acc[i][j] = __builtin_amdgcn_mfma_f32_16x16x32_fp8_fp8(a[i], b[j],
                                                               acc[i][j], 0, 0, 0);
  }

  // ---- ysq: reduce partial sums across the 4 quads ----
#pragma unroll
  for (int j = 0; j < 4; ++j) {
    sq[j] += __shfl_xor(sq[j], 16, 64);
    sq[j] += __shfl_xor(sq[j], 32, 64);
  }

  // ---- epilogue: out = exp(2*cross - ysq - wsq), fire-and-forget ----
  int pj[4];
#pragma unroll
  for (int j = 0; j < 4; ++j) pj[j] = tp0 + rb[j];

#pragma unroll
  for (int i = 0; i < 4; ++i) {
#pragma unroll
    for (int r = 0; r < 4; ++r) {
      const int ch = c0 + wch * 64 + i * 16 + quad * 4 + r;
      const float wsv = wsq[ch];
      float* ob = out + ((size_t)(nb * NCH + ch)) * P_OUT;
#pragma unroll
      for (int j = 0; j < 4; ++j)
        if (rb[j] < nrows)
          ob[pj[j]] = __expf(2.f * acc[i][j][r] - sq[j] - wsv);
    }
  }
}

extern "C" void kernel_launch(void* const* d_in, const int* in_sizes, int n_in,
                              void* d_out, int out_size, void* d_ws, size_t ws_size,
                              hipStream_t stream) {
  const float* x = (const float*)d_in[0];
  const float* w = (const float*)d_in[1];
  float* out = (float*)d_out;
  char* ws = (char*)d_ws;
  // workspace: wb 512*128 fp8 = 65,536 B ; wsq 512*4 = 2,048 B
  u8* wb     = (u8*)ws;
  float* wsq = (float*)(ws + 65536);

  wprep_kernel<<<32, 256, 0, stream>>>(w, wb, wsq);
  gauss_fused_kernel<<<3968, 256, 0, stream>>>(x, wb, wsq, out);
}